// Round 1
// baseline (244.558 us; speedup 1.0000x reference)
//
#include <hip/hip_runtime.h>
#include <hip/hip_bf16.h>

typedef int v4i __attribute__((ext_vector_type(4)));

#define BM 128
#define BN 128
#define BKB 64  // K-bytes (int8 elems) per tile step

// ---------------- pack int32 -> int8 ----------------
__global__ void pack_i32_to_i8(const int* __restrict__ src,
                               signed char* __restrict__ dst, size_t n4) {
    // n4 = n/4; each iteration handles 4 int32 -> 4 bytes
    size_t i = (size_t)blockIdx.x * blockDim.x + threadIdx.x;
    size_t stride = (size_t)gridDim.x * blockDim.x;
    for (size_t j = i; j < n4; j += stride) {
        const int4 v = ((const int4*)src)[j];
        char4 c;
        c.x = (signed char)v.x; c.y = (signed char)v.y;
        c.z = (signed char)v.z; c.w = (signed char)v.w;
        ((char4*)dst)[j] = c;
    }
}

// ---------------- int8 GEMM + fused dequant ----------------
// A: (Mtot, K) int8 row-major; W: (N, K) int8 row-major (i.e. B^T, K-contig)
// out[m][n] = (i32 dot) * sx[m] * ws[n] + bias[n]   (fp32 store)
__global__ __launch_bounds__(256) void i8gemm_kernel(
    const signed char* __restrict__ A,
    const signed char* __restrict__ W,
    const float* __restrict__ sx,
    const float* __restrict__ wsc,
    const float* __restrict__ bias,
    float* __restrict__ C,
    int Mtot, int N, int K)
{
    __shared__ signed char lA[BM * BKB]; // 8 KB
    __shared__ signed char lB[BN * BKB]; // 8 KB

    const int tid  = threadIdx.x;
    const int wave = tid >> 6;
    const int lane = tid & 63;
    const int wr = wave >> 1;   // wave row 0..1 (64-row strip)
    const int wc = wave & 1;    // wave col 0..1 (64-col strip)

    const int bm = blockIdx.x * BM;
    const int bn = blockIdx.y * BN;

    v4i acc[4][4];
#pragma unroll
    for (int i = 0; i < 4; ++i)
#pragma unroll
        for (int j = 0; j < 4; ++j)
#pragma unroll
            for (int e = 0; e < 4; ++e) acc[i][j][e] = 0;

    // staging map: chunk c (0..7) covers rows [c*16, c*16+16), 64B each.
    // wave handles chunks {wave, wave+4}; lane l -> row c*16 + (l>>2), kb (l&3)*16
    const int srow_in = lane >> 2;
    const int skb     = (lane & 3) * 16;

    const signed char* Abase = A + (size_t)bm * K;
    const signed char* Wbase = W + (size_t)bn * K;

    for (int k0 = 0; k0 < K; k0 += BKB) {
#pragma unroll
        for (int r = 0; r < 2; ++r) {
            const int chunk = r * 4 + wave;           // wave-uniform
            const int row   = chunk * 16 + srow_in;   // 0..127
            const signed char* ga = Abase + (size_t)row * K + k0 + skb;
            const signed char* gb = Wbase + (size_t)row * K + k0 + skb;
            signed char* la = lA + chunk * 1024 + lane * 16; // linear per-lane
            signed char* lb = lB + chunk * 1024 + lane * 16;
            __builtin_amdgcn_global_load_lds(
                (const __attribute__((address_space(1))) void*)ga,
                (__attribute__((address_space(3))) void*)la, 16, 0, 0);
            __builtin_amdgcn_global_load_lds(
                (const __attribute__((address_space(1))) void*)gb,
                (__attribute__((address_space(3))) void*)lb, 16, 0, 0);
        }
        __syncthreads();

        // fragments: lane l -> row/col (l&15), k-group (l>>4)*16 bytes
        const int frow = lane & 15;
        const int fkb  = (lane >> 4) * 16;
        v4i afrag[4], bfrag[4];
#pragma unroll
        for (int f = 0; f < 4; ++f) {
            afrag[f] = *(const v4i*)(lA + (size_t)(wr * 64 + f * 16 + frow) * BKB + fkb);
            bfrag[f] = *(const v4i*)(lB + (size_t)(wc * 64 + f * 16 + frow) * BKB + fkb);
        }
#pragma unroll
        for (int i = 0; i < 4; ++i)
#pragma unroll
            for (int j = 0; j < 4; ++j)
                acc[i][j] = __builtin_amdgcn_mfma_i32_16x16x64_i8(
                    afrag[i], bfrag[j], acc[i][j], 0, 0, 0);
        __syncthreads();
    }

    // epilogue: D frag mapping col = lane&15, row = (lane>>4)*4 + reg
    const int cl = lane & 15;
    const int rg = lane >> 4;
    float wsv[4], bv[4];
#pragma unroll
    for (int j = 0; j < 4; ++j) {
        const int col = bn + wc * 64 + j * 16 + cl;
        wsv[j] = wsc[col];
        bv[j]  = bias[col];
    }
#pragma unroll
    for (int i = 0; i < 4; ++i) {
#pragma unroll
        for (int jr = 0; jr < 4; ++jr) {
            const int row = bm + wr * 64 + i * 16 + rg * 4 + jr;
            const float s = sx[row];
#pragma unroll
            for (int j = 0; j < 4; ++j) {
                const int col = bn + wc * 64 + j * 16 + cl;
                const float v = (float)acc[i][j][jr] * s * wsv[j] + bv[j];
                C[(size_t)row * N + col] = v;
            }
        }
    }
}

extern "C" void kernel_launch(void* const* d_in, const int* in_sizes, int n_in,
                              void* d_out, int out_size, void* d_ws, size_t ws_size,
                              hipStream_t stream) {
    const int*   x_q  = (const int*)d_in[0];    // (B,M,K) int8 values in int32
    const float* sx   = (const float*)d_in[1];  // (B,M,1)
    const int*   w_q  = (const int*)d_in[2];    // (N,K) int8 values in int32
    const float* wsc  = (const float*)d_in[3];  // (N,1)
    const float* bias = (const float*)d_in[4];  // (N,)
    float* out = (float*)d_out;

    const int Bb = 4, M = 2048, K = 4096, N = 4096;
    const int Mtot = Bb * M;

    signed char* x8 = (signed char*)d_ws;
    signed char* w8 = x8 + (size_t)Mtot * K;

    const size_t nx = (size_t)Mtot * K;  // 33,554,432
    const size_t nw = (size_t)N * K;     // 16,777,216

    pack_i32_to_i8<<<2048, 256, 0, stream>>>(x_q, x8, nx / 4);
    pack_i32_to_i8<<<1024, 256, 0, stream>>>(w_q, w8, nw / 4);

    dim3 grid(Mtot / BM, N / BN);
    i8gemm_kernel<<<grid, 256, 0, stream>>>(x8, w8, sx, wsc, bias, out, Mtot, N, K);
}

// Round 2
// 190.937 us; speedup vs baseline: 1.2808x; 1.2808x over previous
//
#include <hip/hip_runtime.h>

typedef int v4i __attribute__((ext_vector_type(4)));

constexpr int Kdim = 4096;
constexpr int Ndim = 4096;
constexpr int MtotC = 8192;
constexpr int BM = 256;
constexpr int BN = 256;
constexpr int BKB = 128;          // K-bytes per LDS tile
constexpr int NT = Kdim / BKB;    // 32 K-tiles

// ---------------- pack int32 -> int8 ----------------
__global__ void pack_i32_to_i8(const int* __restrict__ src,
                               signed char* __restrict__ dst, size_t n4) {
    size_t i = (size_t)blockIdx.x * blockDim.x + threadIdx.x;
    size_t stride = (size_t)gridDim.x * blockDim.x;
    for (size_t j = i; j < n4; j += stride) {
        const int4 v = ((const int4*)src)[j];
        char4 c;
        c.x = (signed char)v.x; c.y = (signed char)v.y;
        c.z = (signed char)v.z; c.w = (signed char)v.w;
        ((char4*)dst)[j] = c;
    }
}

// ---------------- int8 GEMM, 256x256 tile, counted-vmcnt pipeline ----------------
// A: (Mtot,K) i8 row-major; W: (N,K) i8 row-major. out = i32dot * sx[m]*ws[n] + bias[n].
__global__ __launch_bounds__(512, 2) void i8gemm_kernel(
    const signed char* __restrict__ A,
    const signed char* __restrict__ W,
    const float* __restrict__ sx,
    const float* __restrict__ wsc,
    const float* __restrict__ bias,
    float* __restrict__ C)
{
    extern __shared__ signed char smem[]; // 2 bufs x (A 32KB + B 32KB) = 128KB

    const int tid  = threadIdx.x;
    const int wave = tid >> 6;
    const int lane = tid & 63;
    const int wr = wave >> 2;     // 0..1  (128-row strip)
    const int wc = wave & 3;      // 0..3  (64-col strip)

    // XCD-aware bijective swizzle: 512 wgs, 8 XCDs, 64 per chunk
    int wg = blockIdx.x;
    wg = (wg & 7) * 64 + (wg >> 3);
    const int bm = (wg & 31) * BM;   // 32 row panels (fastest within chunk)
    const int bn = (wg >> 5) * BN;   // 16 col panels

    // ---- staging map (per thread: 4 A-loads + 4 B-loads of 16B per K-tile) ----
    // LDS slot si = r*512 + tid  ->  (row = si>>3, slot' = si&7), dest linear si*16.
    // LDS (row, s') holds global 16B-slot  s = s' ^ (row&7)  (XOR involution).
    const int srow = tid >> 3;                                  // 0..63
    const int ssw  = ((tid & 7) ^ ((tid >> 3) & 7)) * 16;       // pre-swizzled source slot
    const signed char* Ag = A + (size_t)(bm + srow) * Kdim + ssw;
    const signed char* Wg = W + (size_t)(bn + srow) * Kdim + ssw;

    auto STAGE = [&](int kt, int buf) {
        signed char* dA = smem + buf * 65536 + tid * 16;
        signed char* dB = dA + 32768;
        const signed char* sA = Ag + (size_t)kt * BKB;
        const signed char* sB = Wg + (size_t)kt * BKB;
#pragma unroll
        for (int r = 0; r < 4; ++r)
            __builtin_amdgcn_global_load_lds(
                (const __attribute__((address_space(1))) void*)(sA + (size_t)r * 64 * Kdim),
                (__attribute__((address_space(3))) void*)(dA + r * 8192), 16, 0, 0);
#pragma unroll
        for (int r = 0; r < 4; ++r)
            __builtin_amdgcn_global_load_lds(
                (const __attribute__((address_space(1))) void*)(sB + (size_t)r * 64 * Kdim),
                (__attribute__((address_space(3))) void*)(dB + r * 8192), 16, 0, 0);
    };

    // ---- fragment read map ----
    const int frow = lane & 15;      // row/col within 16x16 frag
    const int fsl  = lane >> 4;      // 16B k-slot within 64B k-half
    const int xr   = frow & 7;       // read-side swizzle (row&7 == frow&7 here)
    const int s0   = ((fsl)     ^ xr) * 16;   // kh=0 swizzled slot byte
    const int s1   = ((4 + fsl) ^ xr) * 16;   // kh=1
    const int aoff = (wr * 128 + frow) * BKB; // + f*2048
    const int boff = (wc * 64  + frow) * BKB; // + g*2048

    v4i acc[8][4];
#pragma unroll
    for (int f = 0; f < 8; ++f)
#pragma unroll
        for (int g = 0; g < 4; ++g)
#pragma unroll
            for (int e = 0; e < 4; ++e) acc[f][g][e] = 0;

    auto COMPUTE = [&](int buf) {
        const signed char* bA = smem + buf * 65536 + aoff;
        const signed char* bB = smem + buf * 65536 + 32768 + boff;
        v4i av[8], bv[4];
        // kh = 0
#pragma unroll
        for (int g = 0; g < 4; ++g) bv[g] = *(const v4i*)(bB + g * 2048 + s0);
#pragma unroll
        for (int f = 0; f < 8; ++f) av[f] = *(const v4i*)(bA + f * 2048 + s0);
        __builtin_amdgcn_s_setprio(1);
#pragma unroll
        for (int f = 0; f < 8; ++f)
#pragma unroll
            for (int g = 0; g < 4; ++g)
                acc[f][g] = __builtin_amdgcn_mfma_i32_16x16x64_i8(av[f], bv[g], acc[f][g], 0, 0, 0);
        __builtin_amdgcn_s_setprio(0);
        // kh = 1
#pragma unroll
        for (int g = 0; g < 4; ++g) bv[g] = *(const v4i*)(bB + g * 2048 + s1);
#pragma unroll
        for (int f = 0; f < 8; ++f) av[f] = *(const v4i*)(bA + f * 2048 + s1);
        __builtin_amdgcn_s_setprio(1);
#pragma unroll
        for (int f = 0; f < 8; ++f)
#pragma unroll
            for (int g = 0; g < 4; ++g)
                acc[f][g] = __builtin_amdgcn_mfma_i32_16x16x64_i8(av[f], bv[g], acc[f][g], 0, 0, 0);
        __builtin_amdgcn_s_setprio(0);
    };

    // ---- prologue: stage tiles 0,1; wait tile 0 (8 newest stay in flight) ----
    STAGE(0, 0);
    STAGE(1, 1);
    asm volatile("s_waitcnt vmcnt(8)" ::: "memory");
    __builtin_amdgcn_s_barrier();

    // ---- main loop: compute t from buf[t&1]; then restage that buf with t+2 ----
    for (int t = 0; t < NT; ++t) {
        const int cur = t & 1;
        COMPUTE(cur);
        __builtin_amdgcn_sched_barrier(0);
        asm volatile("s_waitcnt lgkmcnt(0)" ::: "memory");
        __builtin_amdgcn_s_barrier();          // all reads of buf[cur] done
        if (t + 2 < NT) {
            STAGE(t + 2, cur);                 // 8 new loads -> buf[cur]
            asm volatile("s_waitcnt vmcnt(8)" ::: "memory"); // tile t+1 landed
            __builtin_amdgcn_s_barrier();
        } else if (t + 1 < NT) {
            asm volatile("s_waitcnt vmcnt(0)" ::: "memory"); // last tile landed
            __builtin_amdgcn_s_barrier();
        }
    }

    // ---- epilogue: dequant + bias, fp32 store ----
    const int orow0 = bm + wr * 128;
    const int ocol0 = bn + wc * 64;
    float wsv[4], bvv[4];
#pragma unroll
    for (int g = 0; g < 4; ++g) {
        const int col = ocol0 + g * 16 + frow;
        wsv[g] = wsc[col];
        bvv[g] = bias[col];
    }
#pragma unroll
    for (int f = 0; f < 8; ++f) {
#pragma unroll
        for (int jr = 0; jr < 4; ++jr) {
            const int row = orow0 + f * 16 + fsl * 4 + jr;
            const float s = sx[row];
#pragma unroll
            for (int g = 0; g < 4; ++g) {
                const int col = ocol0 + g * 16 + frow;
                C[(size_t)row * Ndim + col] = (float)acc[f][g][jr] * s * wsv[g] + bvv[g];
            }
        }
    }
}

extern "C" void kernel_launch(void* const* d_in, const int* in_sizes, int n_in,
                              void* d_out, int out_size, void* d_ws, size_t ws_size,
                              hipStream_t stream) {
    (void)in_sizes; (void)n_in; (void)out_size; (void)ws_size;
    const int*   x_q  = (const int*)d_in[0];
    const float* sx   = (const float*)d_in[1];
    const int*   w_q  = (const int*)d_in[2];
    const float* wsc  = (const float*)d_in[3];
    const float* bias = (const float*)d_in[4];
    float* out = (float*)d_out;

    signed char* x8 = (signed char*)d_ws;
    signed char* w8 = x8 + (size_t)MtotC * Kdim;

    const size_t nx = (size_t)MtotC * Kdim;   // 32 Mi
    const size_t nw = (size_t)Ndim * Kdim;    // 16 Mi

    pack_i32_to_i8<<<2048, 256, 0, stream>>>(x_q, x8, nx / 4);
    pack_i32_to_i8<<<1024, 256, 0, stream>>>(w_q, w8, nw / 4);

    static bool attr_set = false;
    if (!attr_set) {  // idempotent host-side attribute, not a stream op
        hipFuncSetAttribute((const void*)i8gemm_kernel,
                            hipFuncAttributeMaxDynamicSharedMemorySize, 131072);
        attr_set = true;
    }

    const int nwg = (MtotC / BM) * (Ndim / BN);  // 32*16 = 512
    i8gemm_kernel<<<nwg, 512, 131072, stream>>>(x8, w8, sx, wsc, bias, out);
}

// Round 4
// 189.537 us; speedup vs baseline: 1.2903x; 1.0074x over previous
//
#include <hip/hip_runtime.h>

typedef int v4i __attribute__((ext_vector_type(4)));

constexpr int Kdim = 4096;
constexpr int Ndim = 4096;
constexpr int MtotC = 8192;
constexpr int BM = 256;
constexpr int BN = 256;
constexpr int BKB = 128;          // K-bytes per LDS tile (2 halves of 64B)
constexpr int NT = Kdim / BKB;    // 32 K-tiles

// ---------------- pack int32 -> int8 (both tensors, one launch) ----------------
__global__ void pack_i32_to_i8(const int* __restrict__ xq, const int* __restrict__ wq,
                               signed char* __restrict__ x8, signed char* __restrict__ w8,
                               size_t nx4, size_t nw4) {
    size_t i = (size_t)blockIdx.x * blockDim.x + threadIdx.x;
    size_t stride = (size_t)gridDim.x * blockDim.x;
    size_t tot = nx4 + nw4;
    for (size_t j = i; j < tot; j += stride) {
        if (j < nx4) {
            const int4 v = ((const int4*)xq)[j];
            char4 c;
            c.x = (signed char)v.x; c.y = (signed char)v.y;
            c.z = (signed char)v.z; c.w = (signed char)v.w;
            ((char4*)x8)[j] = c;
        } else {
            const size_t k = j - nx4;
            const int4 v = ((const int4*)wq)[k];
            char4 c;
            c.x = (signed char)v.x; c.y = (signed char)v.y;
            c.z = (signed char)v.z; c.w = (signed char)v.w;
            ((char4*)w8)[k] = c;
        }
    }
}

// ---------------- int8 GEMM, 256x256 tile, 8-phase schedule ----------------
// LDS: 2 bufs x 2 halves x (A 16KB + B 16KB) = 128KB.
// Half h of K-tile t holds K-bytes [t*128 + h*64, +64) for 256 A-rows + 256 B-rows.
// 16B-slot swizzle within a 64B row: slot' = slot ^ ((row>>1)&3)  (2-way = free).
__global__ __launch_bounds__(512, 2) void i8gemm_kernel(
    const signed char* __restrict__ A,
    const signed char* __restrict__ W,
    const float* __restrict__ sx,
    const float* __restrict__ wsc,
    const float* __restrict__ bias,
    float* __restrict__ C)
{
    extern __shared__ signed char smem[];

    const int tid  = threadIdx.x;
    const int wave = tid >> 6;
    const int lane = tid & 63;
    const int wr = wave >> 2;     // 0..1  (128-row strip)
    const int wc = wave & 3;      // 0..3  (64-col strip)

    // XCD-aware swizzle: 8 regions of 8bm x 8bn (per-XCD working set 8MB A + 8MB W)
    const int xr_ = blockIdx.x & 7;
    const int idx = blockIdx.x >> 3;
    const int bm = ((xr_ & 3) * 8 + (idx & 7)) * BM;
    const int bn = ((xr_ >> 2) * 8 + (idx >> 3)) * BN;

    // ---- staging constants (per thread: 1 A + 1 B gload_lds per phase) ----
    const int srow_in = wave * 16 + (lane >> 2);            // 0..127
    const int sslotp  = lane & 3;                           // LDS slot'
    const int gslot   = sslotp ^ ((srow_in >> 1) & 3);      // pre-inverse-swizzled global slot
    const signed char* Ag = A + (size_t)(bm + srow_in) * Kdim + gslot * 16;
    const signed char* Wg = W + (size_t)(bn + srow_in) * Kdim + gslot * 16;
    const int sdst = srow_in * 64 + sslotp * 16;            // within-half LDS offset

    // ---- fragment read constants ----
    const int frow = lane & 15;
    const int fsl  = lane >> 4;
    const int rsw  = ((fsl ^ ((frow >> 1) & 3)) << 4);      // swizzled 16B slot byte
    const int aro  = (wr * 128 + frow) * 64 + rsw;          // + f*1024 + half*32768
    const int bro  = 16384 + (wc * 64 + frow) * 64 + rsw;   // + g*1024 + half*32768

    v4i acc[8][4];
#pragma unroll
    for (int f = 0; f < 8; ++f)
#pragma unroll
        for (int g = 0; g < 4; ++g)
#pragma unroll
            for (int e = 0; e < 4; ++e) acc[f][g][e] = 0;

#define STG(KT, HALF, RB) do {                                                         \
    __builtin_amdgcn_global_load_lds(                                                  \
        (const __attribute__((address_space(1))) void*)(Ag + (size_t)(RB) * Kdim + (KT) * BKB + (HALF) * 64), \
        (__attribute__((address_space(3))) void*)(smem + ((KT) & 1) * 65536 + (HALF) * 32768 + (RB) * 64 + sdst), \
        16, 0, 0);                                                                     \
    __builtin_amdgcn_global_load_lds(                                                  \
        (const __attribute__((address_space(1))) void*)(Wg + (size_t)(RB) * Kdim + (KT) * BKB + (HALF) * 64), \
        (__attribute__((address_space(3))) void*)(smem + ((KT) & 1) * 65536 + (HALF) * 32768 + 16384 + (RB) * 64 + sdst), \
        16, 0, 0);                                                                     \
} while (0)

#define BAR   __builtin_amdgcn_s_barrier()
#define LGKM0 asm volatile("s_waitcnt lgkmcnt(0)" ::: "memory")
#define PRIO1 __builtin_amdgcn_s_setprio(1)
#define PRIO0 __builtin_amdgcn_s_setprio(0)

#define PH_READ_AB(HALF) do {                                                          \
    _Pragma("unroll") for (int g_ = 0; g_ < 4; ++g_)                                   \
        bv[g_] = *(const v4i*)(bufb + (HALF) * 32768 + bro + g_ * 1024);               \
    _Pragma("unroll") for (int f_ = 0; f_ < 4; ++f_)                                   \
        av[f_] = *(const v4i*)(bufb + (HALF) * 32768 + aro + f_ * 1024);               \
} while (0)

#define PH_READ_A4(HALF) do {                                                          \
    _Pragma("unroll") for (int f_ = 0; f_ < 4; ++f_)                                   \
        av[f_] = *(const v4i*)(bufb + (HALF) * 32768 + aro + (4 + f_) * 1024);         \
} while (0)

#define MFMA_BLOCK(FB) do {                                                            \
    _Pragma("unroll") for (int f_ = 0; f_ < 4; ++f_)                                   \
    _Pragma("unroll") for (int g_ = 0; g_ < 4; ++g_)                                   \
        acc[(FB) + f_][g_] = __builtin_amdgcn_mfma_i32_16x16x64_i8(                    \
            av[f_], bv[g_], acc[(FB) + f_][g_], 0, 0, 0);                              \
} while (0)

// One K-tile = 4 phases. Staging: ph1-2 -> (U+1).H1, ph3-4 -> (U+2).H0.
// Counted waits: end of ph2 drains U.H1 (for ph3); end of ph4 drains (U+1).H0.
#define TILE_BODY(U, DOS12, DOS34, W2STR, DOW4, W4STR) do {                            \
    signed char* bufb = smem + ((U) & 1) * 65536;                                      \
    v4i av[4], bv[4];                                                                  \
    /* phase 1: kh0, f0-3 x g0-3 */                                                    \
    PH_READ_AB(0);                                                                     \
    if (DOS12) STG((U) + 1, 1, 0);                                                     \
    BAR; LGKM0; PRIO1; MFMA_BLOCK(0); PRIO0; BAR;                                      \
    /* phase 2: kh0, f4-7 x g0-3 */                                                    \
    PH_READ_A4(0);                                                                     \
    if (DOS12) STG((U) + 1, 1, 128);                                                   \
    BAR; LGKM0; PRIO1; MFMA_BLOCK(4); PRIO0;                                           \
    asm volatile("s_waitcnt " W2STR ::: "memory"); BAR;                                \
    /* phase 3: kh1, f0-3 x g0-3 */                                                    \
    PH_READ_AB(1);                                                                     \
    if (DOS34) STG((U) + 2, 0, 0);                                                     \
    BAR; LGKM0; PRIO1; MFMA_BLOCK(0); PRIO0; BAR;                                      \
    /* phase 4: kh1, f4-7 x g0-3 */                                                    \
    PH_READ_A4(1);                                                                     \
    if (DOS34) STG((U) + 2, 0, 128);                                                   \
    BAR; LGKM0; PRIO1; MFMA_BLOCK(4); PRIO0;                                           \
    if (DOW4) { asm volatile("s_waitcnt " W4STR ::: "memory"); }                       \
    BAR;                                                                               \
} while (0)

    // ---- prologue: 0.H0, 0.H1, 1.H0 (12 loads/wave); drain 0.H0 ----
    STG(0, 0, 0);  STG(0, 0, 128);
    STG(0, 1, 0);  STG(0, 1, 128);
    STG(1, 0, 0);  STG(1, 0, 128);
    asm volatile("s_waitcnt vmcnt(8)" ::: "memory");
    BAR;

    for (int u = 0; u < NT - 2; ++u)
        TILE_BODY(u, true, true, "vmcnt(8)", true, "vmcnt(8)");
    TILE_BODY(NT - 2, true,  false, "vmcnt(8)", true,  "vmcnt(4)");
    TILE_BODY(NT - 1, false, false, "vmcnt(0)", false, "vmcnt(0)");

    // ---- epilogue: dequant + bias, fp32 store ----
    const int orow0 = bm + wr * 128;
    const int ocol0 = bn + wc * 64;
    float wsv[4], bvv[4];
#pragma unroll
    for (int g = 0; g < 4; ++g) {
        const int col = ocol0 + g * 16 + frow;
        wsv[g] = wsc[col];
        bvv[g] = bias[col];
    }
#pragma unroll
    for (int f = 0; f < 8; ++f) {
#pragma unroll
        for (int jr = 0; jr < 4; ++jr) {
            const int row = orow0 + f * 16 + fsl * 4 + jr;
            const float s = sx[row];
#pragma unroll
            for (int g = 0; g < 4; ++g) {
                const int col = ocol0 + g * 16 + frow;
                C[(size_t)row * Ndim + col] = (float)acc[f][g][jr] * s * wsv[g] + bvv[g];
            }
        }
    }
#undef STG
#undef BAR
#undef LGKM0
#undef PRIO1
#undef PRIO0
#undef PH_READ_AB
#undef PH_READ_A4
#undef MFMA_BLOCK
#undef TILE_BODY
}

extern "C" void kernel_launch(void* const* d_in, const int* in_sizes, int n_in,
                              void* d_out, int out_size, void* d_ws, size_t ws_size,
                              hipStream_t stream) {
    (void)in_sizes; (void)n_in; (void)out_size; (void)ws_size;
    const int*   x_q  = (const int*)d_in[0];
    const float* sx   = (const float*)d_in[1];
    const int*   w_q  = (const int*)d_in[2];
    const float* wsc  = (const float*)d_in[3];
    const float* bias = (const float*)d_in[4];
    float* out = (float*)d_out;

    signed char* x8 = (signed char*)d_ws;
    signed char* w8 = x8 + (size_t)MtotC * Kdim;

    const size_t nx = (size_t)MtotC * Kdim;   // 32 Mi
    const size_t nw = (size_t)Ndim * Kdim;    // 16 Mi

    pack_i32_to_i8<<<3072, 256, 0, stream>>>(x_q, w_q, x8, w8, nx / 4, nw / 4);

    static bool attr_set = false;
    if (!attr_set) {
        hipFuncSetAttribute((const void*)i8gemm_kernel,
                            hipFuncAttributeMaxDynamicSharedMemorySize, 131072);
        attr_set = true;
    }

    const int nwg = (MtotC / BM) * (Ndim / BN);  // 512
    i8gemm_kernel<<<nwg, 512, 131072, stream>>>(x8, w8, sx, wsc, bias, out);
}